// Round 3
// baseline (7190.775 us; speedup 1.0000x reference)
//
#include <hip/hip_runtime.h>

typedef unsigned short u16;
typedef __attribute__((ext_vector_type(8))) short bf8;   // 8 x bf16 (4 VGPRs) MFMA operand
typedef __attribute__((ext_vector_type(4))) float f4;    // MFMA accumulator

#define DEVI static __device__ __forceinline__

constexpr int Bb = 128, Tt = 512, Dd = 128, Hh = 256, G4 = 1024;
constexpr int CH  = 64;        // timesteps per chunk
constexpr int NCH = Tt / CH;   // 8 chunks
constexpr int MCH = CH * Bb;   // 8192 GEMM rows per chunk

DEVI u16 f2bf(float f) {
  union { float f; unsigned u; } v; v.f = f;
  unsigned r = v.u + 0x7FFFu + ((v.u >> 16) & 1u);  // RNE
  return (u16)(r >> 16);
}
DEVI float bf2f(u16 b) { union { unsigned u; float f; } v; v.u = ((unsigned)b) << 16; return v.f; }
DEVI float sigm(float x) { return 1.f / (1.f + __expf(-x)); }
DEVI float tanh_f(float x) {
  float e = __expf(-2.f * fabsf(x));
  float t = (1.f - e) / (1.f + e);
  return copysignf(t, x);
}
DEVI f4 mfma16(bf8 a, bf8 b, f4 c) {
  return __builtin_amdgcn_mfma_f32_16x16x32_bf16(a, b, c, 0, 0, 0);
}

// ---------- prep kernels ----------

__global__ void k_prep_x(const float* __restrict__ X, u16* __restrict__ Xhi, u16* __restrict__ Xlo) {
  size_t idx = (size_t)blockIdx.x * 256 + threadIdx.x;      // (b*T+t)*D + d
  int d = (int)(idx % Dd);
  size_t bt = idx / Dd;
  int b = (int)(bt / Tt), t = (int)(bt % Tt);
  float x = X[idx];
  u16 hi = f2bf(x);
  u16 lo = f2bf(x - bf2f(hi));
  size_t o = ((size_t)t * Bb + b) * Dd + d;
  Xhi[o] = hi; Xlo[o] = lo;
}

__global__ void k_split(const float* __restrict__ W, u16* __restrict__ hi_, u16* __restrict__ lo_) {
  size_t idx = (size_t)blockIdx.x * 256 + threadIdx.x;
  float v = W[idx];
  u16 hi = f2bf(v);
  hi_[idx] = hi;
  lo_[idx] = f2bf(v - bf2f(hi));
}

// Whh[4H,H] -> fragment-linear bf16 W2: offset jt*4096 + kt*512 + lane*8 + i
// holds B[k][col], col = jt*16+(lane&15), k = kt*32+(lane>>4)*8+i
__global__ void k_prep_whh(const float* __restrict__ Whh, u16* __restrict__ W2) {
  int idx = blockIdx.x * 256 + threadIdx.x;           // 4H*H = 262144
  int i = idx & 7, lane = (idx >> 3) & 63, kt = (idx >> 9) & 7, jt = idx >> 12;
  int jp = (jt << 4) + (lane & 15);
  int k  = ((lane >> 4) << 3) + i + (kt << 5);
  W2[idx] = f2bf(Whh[(size_t)jp * Hh + k]);
}

__global__ void k_bias(const float* __restrict__ a, const float* __restrict__ b, float* __restrict__ o) {
  int i = blockIdx.x * 256 + threadIdx.x;
  if (i < G4) o[i] = a[i] + b[i];
}

// ---------- input GEMM: gates = A[M,K] @ W[1024,K]^T + bias, written in XGF layout ----------
template <int K, bool ALO>
__global__ void __launch_bounds__(256) k_gemm(
    const u16* __restrict__ Ahi, const u16* __restrict__ Alo,
    const u16* __restrict__ Whi, const u16* __restrict__ Wlo,
    const float* __restrict__ bias, float* __restrict__ Cout) {
  __shared__ u16 AsH[128][32];
  __shared__ u16 AsL[128][32];
  const int tid = threadIdx.x, l = tid & 63;
  const int w = tid >> 6, wm = w >> 1, wn = w & 1;
  const int lrow = l & 15, lk = (l >> 4) << 3;
  const size_t m0 = (size_t)blockIdx.x * 128;
  const int n0 = blockIdx.y * 128;

  f4 acc[4][4];
  size_t colK[4];
#pragma unroll
  for (int ni = 0; ni < 4; ++ni) {
    int col = n0 + wn * 64 + ni * 16 + lrow;
    float bv = bias[col];
    colK[ni] = (size_t)col * K + lk;
#pragma unroll
    for (int mi = 0; mi < 4; ++mi) {
      acc[mi][ni][0] = bv; acc[mi][ni][1] = bv; acc[mi][ni][2] = bv; acc[mi][ni][3] = bv;
    }
  }

  for (int kk = 0; kk < K; kk += 32) {
    __syncthreads();
#pragma unroll
    for (int s = 0; s < 2; ++s) {
      int slot = s * 256 + tid;
      int r = slot >> 2, kg = (slot & 3) << 3;
      *(bf8*)&AsH[r][kg] = *(const bf8*)&Ahi[(m0 + r) * K + kk + kg];
      if constexpr (ALO) *(bf8*)&AsL[r][kg] = *(const bf8*)&Alo[(m0 + r) * K + kk + kg];
    }
    __syncthreads();

    bf8 bh[4], bl[4];
#pragma unroll
    for (int ni = 0; ni < 4; ++ni) {
      bh[ni] = *(const bf8*)&Whi[colK[ni] + kk];
      bl[ni] = *(const bf8*)&Wlo[colK[ni] + kk];
    }
    bf8 ah[4], al[4];
#pragma unroll
    for (int mi = 0; mi < 4; ++mi) {
      ah[mi] = *(const bf8*)&AsH[wm * 64 + mi * 16 + lrow][lk];
      if constexpr (ALO) al[mi] = *(const bf8*)&AsL[wm * 64 + mi * 16 + lrow][lk];
    }
#pragma unroll
    for (int mi = 0; mi < 4; ++mi)
#pragma unroll
      for (int ni = 0; ni < 4; ++ni) {
        acc[mi][ni] = mfma16(ah[mi], bh[ni], acc[mi][ni]);
        acc[mi][ni] = mfma16(ah[mi], bl[ni], acc[mi][ni]);
        if constexpr (ALO) acc[mi][ni] = mfma16(al[mi], bh[ni], acc[mi][ni]);
      }
  }

  // epilogue: XGF layout, one fully-coalesced f4 store per (mi,ni)
  f4* C4 = (f4*)Cout;
  const int by = blockIdx.y;
#pragma unroll
  for (int mi = 0; mi < 4; ++mi) {
    size_t t8 = ((size_t)blockIdx.x * 8 + wm * 4 + mi);
#pragma unroll
    for (int ni = 0; ni < 4; ++ni) {
      int wr = ((by & 1) << 2) + (wn << 1) + (ni >> 1);
      int qq = ((by >> 1) << 1) + (ni & 1);
      C4[((t8 * 8 + wr) * 8 + qq) * 64 + l] = acc[mi][ni];
    }
  }
}

// ---------- recurrence ----------
// 8 blocks x 512 thr; block bg owns batches [16bg,16bg+16), wave w owns hidden j in [32w,32w+32).
// Whh split: kt 0..4 streamed from L2 (dbuf), kt 5 in VGPRs, kt 6..7 in LDS (staged once).
// Raw s_barrier (LDS-drain only): xg prefetch + h stores float across steps.

#define SLOAD(BUF, KT) { _Pragma("unroll") \
    for (int _q = 0; _q < 8; ++_q) BUF[_q] = *(const bf8*)&W2[wbase[_q] + ((KT) << 9)]; }

#define MF2(B, KT) { _Pragma("unroll") \
    for (int _q = 0; _q < 8; ++_q) acc[_q] = mfma16(af[KT], B[_q], acc[_q]); }

#define LOADXG(T) { const f4* _p = xb + (size_t)(T) * 32768; \
    _Pragma("unroll") for (int _q = 0; _q < 8; ++_q) xgn[_q] = _p[_q << 6]; }

#define BARRIER() asm volatile("s_waitcnt lgkmcnt(0)\ns_barrier" ::: "memory")

__global__ void __launch_bounds__(512, 2) k_recur(
    const float* __restrict__ xg,   // chunk in XGF layout (biases folded)
    const u16* __restrict__ W2,     // fragment-linear Whh bf16
    u16* __restrict__ hseq,         // [T][128][256] bf16
    float* __restrict__ cst,        // [128][256] fp32 carry
    int t0, int write_h) {
  __shared__ u16 hb[2][4096];       // [16][256] bf16, granule-XOR swizzled, double-buffered
  __shared__ u16 wl[65536];         // 128 KB: W2 kt in {6,7}: [(jt*2+kt6)*512 + lane*8 + i]
  const int tid = threadIdx.x, l = tid & 63, w = tid >> 6;
  const int lrow = l & 15, lg = l >> 4;
  const int bg = blockIdx.x;
  const int b_base = bg << 4;

  // stage W2 kt{6,7} stripes into LDS (once per dispatch)
  for (int s = 0; s < 16; ++s) {
    int flat = (s << 9) + tid;      // bf8 granule id 0..8191
    int gofs = ((flat >> 7) << 12) + ((6 + ((flat >> 6) & 1)) << 9) + ((flat & 63) << 3);
    *(bf8*)&wl[flat << 3] = *(const bf8*)&W2[gofs];
  }

  int wbase[8], wlofs[8];
#pragma unroll
  for (int qq = 0; qq < 8; ++qq) {
    int jtg = ((qq >> 1) << 4) + (w << 1) + (qq & 1);
    wbase[qq] = (jtg << 12) + (l << 3);
    wlofs[qq] = (jtg << 10) + (l << 3);
  }
  bf8 wv[8];
#pragma unroll
  for (int qq = 0; qq < 8; ++qq) wv[qq] = *(const bf8*)&W2[wbase[qq] + (5 << 9)];

  f4 c01[2];
  if (t0 == 0) {
#pragma unroll
    for (int q2 = 0; q2 < 2; ++q2)
#pragma unroll
      for (int r = 0; r < 4; ++r) c01[q2][r] = 0.f;
    for (int i = tid; i < 4096; i += 512) hb[0][i] = 0;
  } else {
    const u16* hp = hseq + ((size_t)(t0 - 1) * Bb + b_base) * Hh;
    int b = tid >> 5, g = tid & 31;
    *(bf8*)&hb[0][(b << 8) + ((g ^ b) << 3)] = *(const bf8*)&hp[b * Hh + (g << 3)];
#pragma unroll
    for (int q2 = 0; q2 < 2; ++q2)
#pragma unroll
      for (int r = 0; r < 4; ++r)
        c01[q2][r] = cst[(size_t)(b_base + (lg << 2) + r) * Hh + (w << 5) + (q2 << 4) + lrow];
  }
  __syncthreads();

  const f4* xb = (const f4*)xg + ((size_t)bg * 8 + w) * 512 + l;
  f4 xgn[8];
  LOADXG(0);

  int cur = 0;
  for (int t = 0; t < CH; ++t) {
    bf8 sb0[8], sb1[8];
    SLOAD(sb0, 0);                               // issue kt0 early

    bf8 af[8];                                   // h[b=lrow][k=kt*32+lg*8+i], swizzled
#pragma unroll
    for (int kt = 0; kt < 8; ++kt)
      af[kt] = *(const bf8*)&hb[cur][(lrow << 8) + ((((kt << 2) + lg) ^ lrow) << 3)];

    f4 acc[8];
#pragma unroll
    for (int qq = 0; qq < 8; ++qq) acc[qq] = xgn[qq];

    SLOAD(sb1, 1);
    MF2(sb0, 0);
    SLOAD(sb0, 2);
    MF2(sb1, 1);
    SLOAD(sb1, 3);
    MF2(sb0, 2);
    SLOAD(sb0, 4);
    MF2(sb1, 3);
    if (t + 1 < CH) LOADXG(t + 1);               // after all stream issues: no vmcnt pollution
    MF2(sb0, 4);
    MF2(wv, 5);
    bf8 lb[8];
#pragma unroll
    for (int qq = 0; qq < 8; ++qq) lb[qq] = *(const bf8*)&wl[wlofs[qq]];
    MF2(lb, 6);
#pragma unroll
    for (int qq = 0; qq < 8; ++qq) lb[qq] = *(const bf8*)&wl[wlofs[qq] + 512];
    MF2(lb, 7);

    float hv[2][4];
#pragma unroll
    for (int q2 = 0; q2 < 2; ++q2)
#pragma unroll
      for (int r = 0; r < 4; ++r) {
        float gi = sigm(acc[0 + q2][r]);
        float gf = sigm(acc[2 + q2][r]);
        float gg = tanh_f(acc[4 + q2][r]);
        float go = sigm(acc[6 + q2][r]);
        float cc = gf * c01[q2][r] + gi * gg;
        c01[q2][r] = cc;
        hv[q2][r] = go * tanh_f(cc);
      }

    int nxt = cur ^ 1;
    const bool st = (write_h != 0) || (t == CH - 1);
    u16* hrow = hseq + ((size_t)(t0 + t) * Bb + b_base) * Hh;
#pragma unroll
    for (int q2 = 0; q2 < 2; ++q2)
#pragma unroll
      for (int r = 0; r < 4; ++r) {
        int b = (lg << 2) + r;
        int j = (w << 5) + (q2 << 4) + lrow;
        u16 hbv = f2bf(hv[q2][r]);
        if (st) hrow[b * Hh + j] = hbv;
        hb[nxt][(b << 8) + (((j >> 3) ^ b) << 3) + (j & 7)] = hbv;
      }
    BARRIER();
    cur = nxt;
  }

#pragma unroll
  for (int q2 = 0; q2 < 2; ++q2)
#pragma unroll
    for (int r = 0; r < 4; ++r)
      cst[(size_t)(b_base + (lg << 2) + r) * Hh + (w << 5) + (q2 << 4) + lrow] = c01[q2][r];
}

#undef SLOAD
#undef MF2
#undef LOADXG
#undef BARRIER

// ---------- final FC ----------
__global__ void k_fc(const u16* __restrict__ h2l, const float* __restrict__ Wfc,
                     const float* __restrict__ bfc, float* __restrict__ out) {
  int b = threadIdx.x;
  if (b < Bb) {
    float s = bfc[0];
    for (int j = 0; j < Hh; ++j) s += bf2f(h2l[(size_t)b * Hh + j]) * Wfc[j];
    out[b] = s;
  }
}

// ---------- driver ----------
extern "C" void kernel_launch(void* const* d_in, const int* in_sizes, int n_in,
                              void* d_out, int out_size, void* d_ws, size_t ws_size,
                              hipStream_t stream) {
  const float* X    = (const float*)d_in[0];
  const float* Wih0 = (const float*)d_in[1];
  const float* Whh0 = (const float*)d_in[2];
  const float* bih0 = (const float*)d_in[3];
  const float* bhh0 = (const float*)d_in[4];
  const float* Wih1 = (const float*)d_in[5];
  const float* Whh1 = (const float*)d_in[6];
  const float* bih1 = (const float*)d_in[7];
  const float* bhh1 = (const float*)d_in[8];
  const float* Wfc  = (const float*)d_in[9];
  const float* bfc  = (const float*)d_in[10];

  char* base = (char*)d_ws;
  size_t off = 0;
  auto alloc = [&](size_t bytes) -> char* {
    char* p = base + off;
    off = (off + bytes + 255) & ~(size_t)255;
    return p;
  };

  u16* Xhi = (u16*)alloc((size_t)Bb * Tt * Dd * 2);
  u16* Xlo = (u16*)alloc((size_t)Bb * Tt * Dd * 2);
  u16* W0h = (u16*)alloc((size_t)G4 * Dd * 2);
  u16* W0l = (u16*)alloc((size_t)G4 * Dd * 2);
  u16* W1h = (u16*)alloc((size_t)G4 * Hh * 2);
  u16* W1l = (u16*)alloc((size_t)G4 * Hh * 2);
  u16* W2a = (u16*)alloc((size_t)G4 * Hh * 2);
  u16* W2b = (u16*)alloc((size_t)G4 * Hh * 2);
  float* b0 = (float*)alloc(G4 * 4);
  float* b1 = (float*)alloc(G4 * 4);
  float* xgb = (float*)alloc((size_t)MCH * G4 * 4);     // 33.5 MB chunk buffer (XGF layout)
  u16* h1 = (u16*)alloc((size_t)Tt * Bb * Hh * 2);
  u16* h2 = (u16*)alloc((size_t)Tt * Bb * Hh * 2);
  float* cst = (float*)alloc((size_t)Bb * Hh * 4);

  k_prep_x<<<(Bb * Tt * Dd) / 256, 256, 0, stream>>>(X, Xhi, Xlo);
  k_split<<<(G4 * Dd) / 256, 256, 0, stream>>>(Wih0, W0h, W0l);
  k_split<<<(G4 * Hh) / 256, 256, 0, stream>>>(Wih1, W1h, W1l);
  k_prep_whh<<<(G4 * Hh) / 256, 256, 0, stream>>>(Whh0, W2a);
  k_prep_whh<<<(G4 * Hh) / 256, 256, 0, stream>>>(Whh1, W2b);
  k_bias<<<4, 256, 0, stream>>>(bih0, bhh0, b0);
  k_bias<<<4, 256, 0, stream>>>(bih1, bhh1, b1);

  for (int c = 0; c < NCH; ++c) {
    k_gemm<Dd, true><<<dim3(64, 8), 256, 0, stream>>>(
        Xhi + (size_t)c * MCH * Dd, Xlo + (size_t)c * MCH * Dd, W0h, W0l, b0, xgb);
    k_recur<<<8, 512, 0, stream>>>(xgb, W2a, h1, cst, c * CH, 1);
  }
  for (int c = 0; c < NCH; ++c) {
    k_gemm<Hh, false><<<dim3(64, 8), 256, 0, stream>>>(
        h1 + (size_t)c * MCH * Hh, nullptr, W1h, W1l, b1, xgb);
    k_recur<<<8, 512, 0, stream>>>(xgb, W2b, h2, cst, c * CH, 0);
  }
  k_fc<<<1, 128, 0, stream>>>(h2 + (size_t)(Tt - 1) * Bb * Hh, Wfc, bfc, (float*)d_out);

  (void)in_sizes; (void)n_in; (void)out_size; (void)ws_size;
}

// Round 4
// 4015.356 us; speedup vs baseline: 1.7908x; 1.7908x over previous
//
#include <hip/hip_runtime.h>

typedef unsigned short u16;
typedef __attribute__((ext_vector_type(8))) short bf8;   // 8 x bf16 (4 VGPRs) MFMA operand
typedef __attribute__((ext_vector_type(4))) float f4;    // MFMA accumulator

#define DEVI static __device__ __forceinline__

constexpr int Bb = 128, Tt = 512, Dd = 128, Hh = 256, G4 = 1024;
constexpr int CH  = 64;        // timesteps per chunk
constexpr int NCH = Tt / CH;   // 8 chunks
constexpr int MCH = CH * Bb;   // 8192 GEMM rows per chunk

DEVI u16 f2bf(float f) {
  union { float f; unsigned u; } v; v.f = f;
  unsigned r = v.u + 0x7FFFu + ((v.u >> 16) & 1u);  // RNE
  return (u16)(r >> 16);
}
DEVI float bf2f(u16 b) { union { unsigned u; float f; } v; v.u = ((unsigned)b) << 16; return v.f; }
DEVI float sigm(float x) { return 1.f / (1.f + __expf(-x)); }
DEVI float tanh_f(float x) {
  float e = __expf(-2.f * fabsf(x));
  float t = (1.f - e) / (1.f + e);
  return copysignf(t, x);
}
DEVI f4 mfma16(bf8 a, bf8 b, f4 c) {
  return __builtin_amdgcn_mfma_f32_16x16x32_bf16(a, b, c, 0, 0, 0);
}

// ---------- prep kernels ----------

__global__ void k_prep_x(const float* __restrict__ X, u16* __restrict__ Xhi, u16* __restrict__ Xlo) {
  size_t idx = (size_t)blockIdx.x * 256 + threadIdx.x;      // (b*T+t)*D + d
  int d = (int)(idx % Dd);
  size_t bt = idx / Dd;
  int b = (int)(bt / Tt), t = (int)(bt % Tt);
  float x = X[idx];
  u16 hi = f2bf(x);
  u16 lo = f2bf(x - bf2f(hi));
  size_t o = ((size_t)t * Bb + b) * Dd + d;
  Xhi[o] = hi; Xlo[o] = lo;
}

__global__ void k_split(const float* __restrict__ W, u16* __restrict__ hi_, u16* __restrict__ lo_) {
  size_t idx = (size_t)blockIdx.x * 256 + threadIdx.x;
  float v = W[idx];
  u16 hi = f2bf(v);
  hi_[idx] = hi;
  lo_[idx] = f2bf(v - bf2f(hi));
}

// Whh[4H,H] -> fragment-linear bf16 W2: offset jtg*4096 + kt*512 + lane*8 + i
// holds B[k][col], col = (jtg&15)*16... col = jt*16+(lane&15) with jtg = q*16+jt,
// gate col_global = q*256 + jt*16 + (lane&15), k = kt*32+(lane>>4)*8+i
__global__ void k_prep_whh(const float* __restrict__ Whh, u16* __restrict__ W2) {
  int idx = blockIdx.x * 256 + threadIdx.x;           // 4H*H = 262144
  int i = idx & 7, lane = (idx >> 3) & 63, kt = (idx >> 9) & 7, jtg = idx >> 12;
  int jp = (jtg << 4) + (lane & 15);
  int k  = ((lane >> 4) << 3) + i + (kt << 5);
  W2[idx] = f2bf(Whh[(size_t)jp * Hh + k]);
}

__global__ void k_bias(const float* __restrict__ a, const float* __restrict__ b, float* __restrict__ o) {
  int i = blockIdx.x * 256 + threadIdx.x;
  if (i < G4) o[i] = a[i] + b[i];
}

__global__ void k_zero(int* __restrict__ p, int n) {
  int i = blockIdx.x * 256 + threadIdx.x;
  if (i < n) p[i] = 0;
}

// ---------- input GEMM: gates = A[M,K] @ W[1024,K]^T + bias, written in XGF layout ----------
// XGF f4 index: ((((t*8 + g)*8 + s)*2 + w)*4 + q)*64 + lane
//   t = chunk-local timestep (= blockIdx.x), b = g*16 + (lane>>4)*4 + r, col = q*256 + s*32 + w*16 + (lane&15)
template <int K, bool ALO>
__global__ void __launch_bounds__(256) k_gemm(
    const u16* __restrict__ Ahi, const u16* __restrict__ Alo,
    const u16* __restrict__ Whi, const u16* __restrict__ Wlo,
    const float* __restrict__ bias, float* __restrict__ Cout) {
  __shared__ u16 AsH[128][32];
  __shared__ u16 AsL[128][32];
  const int tid = threadIdx.x, l = tid & 63;
  const int w = tid >> 6, wm = w >> 1, wn = w & 1;
  const int lrow = l & 15, lk = (l >> 4) << 3;
  const size_t m0 = (size_t)blockIdx.x * 128;
  const int n0 = blockIdx.y * 128;

  f4 acc[4][4];
  size_t colK[4];
#pragma unroll
  for (int ni = 0; ni < 4; ++ni) {
    int col = n0 + wn * 64 + ni * 16 + lrow;
    float bv = bias[col];
    colK[ni] = (size_t)col * K + lk;
#pragma unroll
    for (int mi = 0; mi < 4; ++mi) {
      acc[mi][ni][0] = bv; acc[mi][ni][1] = bv; acc[mi][ni][2] = bv; acc[mi][ni][3] = bv;
    }
  }

  for (int kk = 0; kk < K; kk += 32) {
    __syncthreads();
#pragma unroll
    for (int s = 0; s < 2; ++s) {
      int slot = s * 256 + tid;
      int r = slot >> 2, kg = (slot & 3) << 3;
      *(bf8*)&AsH[r][kg] = *(const bf8*)&Ahi[(m0 + r) * K + kk + kg];
      if constexpr (ALO) *(bf8*)&AsL[r][kg] = *(const bf8*)&Alo[(m0 + r) * K + kk + kg];
    }
    __syncthreads();

    bf8 bh[4], bl[4];
#pragma unroll
    for (int ni = 0; ni < 4; ++ni) {
      bh[ni] = *(const bf8*)&Whi[colK[ni] + kk];
      bl[ni] = *(const bf8*)&Wlo[colK[ni] + kk];
    }
    bf8 ah[4], al[4];
#pragma unroll
    for (int mi = 0; mi < 4; ++mi) {
      ah[mi] = *(const bf8*)&AsH[wm * 64 + mi * 16 + lrow][lk];
      if constexpr (ALO) al[mi] = *(const bf8*)&AsL[wm * 64 + mi * 16 + lrow][lk];
    }
#pragma unroll
    for (int mi = 0; mi < 4; ++mi)
#pragma unroll
      for (int ni = 0; ni < 4; ++ni) {
        acc[mi][ni] = mfma16(ah[mi], bh[ni], acc[mi][ni]);
        acc[mi][ni] = mfma16(ah[mi], bl[ni], acc[mi][ni]);
        if constexpr (ALO) acc[mi][ni] = mfma16(al[mi], bh[ni], acc[mi][ni]);
      }
  }

  // epilogue: XGF layout, one fully-coalesced f4 store per (mi,ni)
  f4* C4 = (f4*)Cout;
  const int by = blockIdx.y;
#pragma unroll
  for (int mi = 0; mi < 4; ++mi) {
    int gg = wm * 4 + mi;                       // batch-group
#pragma unroll
    for (int ni = 0; ni < 4; ++ni) {
      int colb = by * 128 + wn * 64 + ni * 16;  // col base (lrow = 0)
      int q  = colb >> 8;
      int ss = (colb >> 5) & 7;
      int wt = (colb >> 4) & 1;
      C4[(((((size_t)blockIdx.x * 8 + gg) * 8 + ss) * 2 + wt) * 4 + q) * 64 + l] = acc[mi][ni];
    }
  }
}

// ---------- recurrence: 64 blocks (8 groups x 8 j-slices) x 128 thr (2 waves) ----------
// Block (g,s): batches [16g,16g+16), hidden j in [32s,32s+32); wave w owns jt = 2s+w.
// Whh slice (8 jtg x 8 kt x 1KB = 64 KB) is LDS-resident. Per step: 32 MFMA/wave into
// acc[q], q = gate type (all 4 gates register-local per thread -> nonlin in-regs).
// Cross-block h exchange per step via hseq + agent-scope release/acquire counters.
__global__ void __launch_bounds__(128) k_recur(
    const float* __restrict__ xg,   // chunk in XGF layout (biases folded)
    const u16* __restrict__ W2,     // fragment-linear Whh bf16
    u16* __restrict__ hseq,         // [T][128][256] bf16 (also the exchange medium)
    float* __restrict__ cst,        // [128][256] fp32 carry
    int* __restrict__ cnt,          // [T][8] step counters (zeroed each launch)
    int t0) {
  __shared__ u16 wlds[32768];       // 64 KB: [jl][kt][512], jl = q*2 + jj
  __shared__ u16 hb[2][4096];       // [16][256] bf16, granule-XOR swizzled, dbuf
  const int tid = threadIdx.x, l = tid & 63, w = tid >> 6;   // w in {0,1}
  const int lrow = l & 15, lg = l >> 4;
  const int g = blockIdx.x & 7, s = blockIdx.x >> 3;
  const int b_base = g << 4;
  const int jmy = (s << 5) + (w << 4) + lrow;   // my hidden column

  // stage W slice: granule f -> jl = f>>9, kt = (f>>6)&7, e = f&63; jtg = (jl>>1)*16 + 2s + (jl&1)
  for (int u = 0; u < 32; ++u) {
    int f = u * 128 + tid;
    int jl = f >> 9, kt = (f >> 6) & 7, e = f & 63;
    int jtg = ((jl >> 1) << 4) + (s << 1) + (jl & 1);
    *(bf8*)&wlds[f << 3] = *(const bf8*)&W2[((size_t)jtg << 12) + (kt << 9) + (e << 3)];
  }

  float cc4[4];                     // c for b = lg*4+rr, j = jmy
  if (t0 == 0) {
    cc4[0] = cc4[1] = cc4[2] = cc4[3] = 0.f;
    for (int i = tid; i < 4096; i += 128) hb[0][i] = 0;
  } else {
#pragma unroll
    for (int rr = 0; rr < 4; ++rr)
      cc4[rr] = cst[(size_t)(b_base + (lg << 2) + rr) * Hh + jmy];
    const u16* hp = hseq + ((size_t)(t0 - 1) * Bb + b_base) * Hh;
    int b = tid >> 3, gr = tid & 7;
#pragma unroll
    for (int u = 0; u < 4; ++u) {
      int g8 = (gr << 2) + u;
      *(bf8*)&hb[0][(b << 8) + ((g8 ^ b) << 3)] = *(const bf8*)&hp[(size_t)b * Hh + (g8 << 3)];
    }
  }
  __syncthreads();

  const f4* xb = (const f4*)xg + ((((size_t)g * 8 + s) * 2 + w) * 4) * 64 + l;
  f4 xgn[4];
#pragma unroll
  for (int q = 0; q < 4; ++q) xgn[q] = xb[q << 6];

  int cur = 0;
  for (int t = 0; t < CH; ++t) {
    bf8 af[8];
#pragma unroll
    for (int kt = 0; kt < 8; ++kt)
      af[kt] = *(const bf8*)&hb[cur][(lrow << 8) + ((((kt << 2) + lg) ^ lrow) << 3)];

    f4 acc[4];
#pragma unroll
    for (int q = 0; q < 4; ++q) acc[q] = xgn[q];

    // kt-major, B double-buffered at kt granularity; 4 independent acc chains
    bf8 b0[4], b1[4];
#pragma unroll
    for (int q = 0; q < 4; ++q)
      b0[q] = *(const bf8*)&wlds[(((((q << 1) | w) << 3) | 0) << 9) + (l << 3)];
#pragma unroll
    for (int kt = 0; kt < 8; ++kt) {
      bf8* bc = (kt & 1) ? b1 : b0;
      bf8* bn = (kt & 1) ? b0 : b1;
      if (kt < 7) {
#pragma unroll
        for (int q = 0; q < 4; ++q)
          bn[q] = *(const bf8*)&wlds[(((((q << 1) | w) << 3) | (kt + 1)) << 9) + (l << 3)];
      }
#pragma unroll
      for (int q = 0; q < 4; ++q) acc[q] = mfma16(af[kt], bc[q], acc[q]);
    }

    if (t + 1 < CH) {
#pragma unroll
      for (int q = 0; q < 4; ++q) xgn[q] = xb[(size_t)(t + 1) * 32768 + (q << 6)];
    }

    u16 hv[4];
#pragma unroll
    for (int rr = 0; rr < 4; ++rr) {
      float gi = sigm(acc[0][rr]);
      float gf = sigm(acc[1][rr]);
      float gg = tanh_f(acc[2][rr]);
      float go = sigm(acc[3][rr]);
      float c2 = gf * cc4[rr] + gi * gg;
      cc4[rr] = c2;
      hv[rr] = f2bf(go * tanh_f(c2));
    }

    const int tg = t0 + t;
    u16* hrow = hseq + ((size_t)tg * Bb + b_base) * Hh;
#pragma unroll
    for (int rr = 0; rr < 4; ++rr)
      hrow[(size_t)((lg << 2) + rr) * Hh + jmy] = hv[rr];

    if (t + 1 < CH) {
      __syncthreads();              // drains vmcnt: all h stores in L2 before flag
      if (tid == 0) {
        __hip_atomic_fetch_add(&cnt[(tg << 3) + g], 1, __ATOMIC_RELEASE,
                               __HIP_MEMORY_SCOPE_AGENT);
        while (__hip_atomic_load(&cnt[(tg << 3) + g], __ATOMIC_ACQUIRE,
                                 __HIP_MEMORY_SCOPE_AGENT) < 8)
          __builtin_amdgcn_s_sleep(1);
      }
      __syncthreads();
      int nxt = cur ^ 1;
      const u16* hp = hseq + ((size_t)tg * Bb + b_base) * Hh;
      int b = tid >> 3, gr = tid & 7;
#pragma unroll
      for (int u = 0; u < 4; ++u) {
        int g8 = (gr << 2) + u;
        *(bf8*)&hb[nxt][(b << 8) + ((g8 ^ b) << 3)] = *(const bf8*)&hp[(size_t)b * Hh + (g8 << 3)];
      }
      __syncthreads();
      cur = nxt;
    }
  }

#pragma unroll
  for (int rr = 0; rr < 4; ++rr)
    cst[(size_t)(b_base + (lg << 2) + rr) * Hh + jmy] = cc4[rr];
}

// ---------- final FC ----------
__global__ void k_fc(const u16* __restrict__ h2l, const float* __restrict__ Wfc,
                     const float* __restrict__ bfc, float* __restrict__ out) {
  int b = threadIdx.x;
  if (b < Bb) {
    float s = bfc[0];
    for (int j = 0; j < Hh; ++j) s += bf2f(h2l[(size_t)b * Hh + j]) * Wfc[j];
    out[b] = s;
  }
}

// ---------- driver ----------
extern "C" void kernel_launch(void* const* d_in, const int* in_sizes, int n_in,
                              void* d_out, int out_size, void* d_ws, size_t ws_size,
                              hipStream_t stream) {
  const float* X    = (const float*)d_in[0];
  const float* Wih0 = (const float*)d_in[1];
  const float* Whh0 = (const float*)d_in[2];
  const float* bih0 = (const float*)d_in[3];
  const float* bhh0 = (const float*)d_in[4];
  const float* Wih1 = (const float*)d_in[5];
  const float* Whh1 = (const float*)d_in[6];
  const float* bih1 = (const float*)d_in[7];
  const float* bhh1 = (const float*)d_in[8];
  const float* Wfc  = (const float*)d_in[9];
  const float* bfc  = (const float*)d_in[10];

  char* base = (char*)d_ws;
  size_t off = 0;
  auto alloc = [&](size_t bytes) -> char* {
    char* p = base + off;
    off = (off + bytes + 255) & ~(size_t)255;
    return p;
  };

  u16* Xhi = (u16*)alloc((size_t)Bb * Tt * Dd * 2);
  u16* Xlo = (u16*)alloc((size_t)Bb * Tt * Dd * 2);
  u16* W0h = (u16*)alloc((size_t)G4 * Dd * 2);
  u16* W0l = (u16*)alloc((size_t)G4 * Dd * 2);
  u16* W1h = (u16*)alloc((size_t)G4 * Hh * 2);
  u16* W1l = (u16*)alloc((size_t)G4 * Hh * 2);
  u16* W2a = (u16*)alloc((size_t)G4 * Hh * 2);
  u16* W2b = (u16*)alloc((size_t)G4 * Hh * 2);
  float* b0 = (float*)alloc(G4 * 4);
  float* b1 = (float*)alloc(G4 * 4);
  float* xgb = (float*)alloc((size_t)MCH * G4 * 4);     // 33.5 MB chunk buffer (XGF layout)
  u16* h1 = (u16*)alloc((size_t)Tt * Bb * Hh * 2);
  u16* h2 = (u16*)alloc((size_t)Tt * Bb * Hh * 2);
  float* cst = (float*)alloc((size_t)Bb * Hh * 4);
  int* cnt = (int*)alloc((size_t)2 * Tt * 8 * 4);       // per-layer [T][8] counters

  k_zero<<<(2 * Tt * 8 + 255) / 256, 256, 0, stream>>>(cnt, 2 * Tt * 8);
  k_prep_x<<<(Bb * Tt * Dd) / 256, 256, 0, stream>>>(X, Xhi, Xlo);
  k_split<<<(G4 * Dd) / 256, 256, 0, stream>>>(Wih0, W0h, W0l);
  k_split<<<(G4 * Hh) / 256, 256, 0, stream>>>(Wih1, W1h, W1l);
  k_prep_whh<<<(G4 * Hh) / 256, 256, 0, stream>>>(Whh0, W2a);
  k_prep_whh<<<(G4 * Hh) / 256, 256, 0, stream>>>(Whh1, W2b);
  k_bias<<<4, 256, 0, stream>>>(bih0, bhh0, b0);
  k_bias<<<4, 256, 0, stream>>>(bih1, bhh1, b1);

  for (int c = 0; c < NCH; ++c) {
    k_gemm<Dd, true><<<dim3(64, 8), 256, 0, stream>>>(
        Xhi + (size_t)c * MCH * Dd, Xlo + (size_t)c * MCH * Dd, W0h, W0l, b0, xgb);
    k_recur<<<64, 128, 0, stream>>>(xgb, W2a, h1, cst, cnt, c * CH);
  }
  for (int c = 0; c < NCH; ++c) {
    k_gemm<Hh, false><<<dim3(64, 8), 256, 0, stream>>>(
        h1 + (size_t)c * MCH * Hh, nullptr, W1h, W1l, b1, xgb);
    k_recur<<<64, 128, 0, stream>>>(xgb, W2b, h2, cst, cnt + Tt * 8, c * CH);
  }
  k_fc<<<1, 128, 0, stream>>>(h2 + (size_t)(Tt - 1) * Bb * Hh, Wfc, bfc, (float*)d_out);

  (void)in_sizes; (void)n_in; (void)out_size; (void)ws_size;
}